// Round 9
// baseline (101.281 us; speedup 1.0000x reference)
//
#include <hip/hip_runtime.h>
#include <math.h>

#define CC 64
#define HWN 4096
#define QB 64            // q per block; ALL 8 waves compute the same 64 q
#define KSPLIT 8         // each wave privately owns 512 k
#define KT 32
#define NITER (HWN / KSPLIT / KT)   // 16 chunks per wave
#define NKC (HWN / KT)              // 128 k-chunks per batch

typedef __attribute__((ext_vector_type(8))) short bf16x8;
typedef __attribute__((ext_vector_type(4))) short bf16x4;
typedef __attribute__((ext_vector_type(4))) float f32x4;

// precomputed bf16 operand layouts (written by prep_kernel every launch)
__device__ __align__(16) unsigned short g_bgT[4][HWN][CC];       // (bg*sb)^T [b][k][c]
__device__ __align__(16) unsigned short g_bgN[4][NKC][CC][KT];   // bf16(bg) chunk-major
__device__ __align__(16) unsigned short g_fgT[4][HWN][CC];       // (fg*sf)^T [b][q][c]

static __device__ __forceinline__ unsigned int f2bf(float x) {   // RNE
  union { float f; unsigned int u; } v; v.f = x;
  return (v.u + 0x7fffu + ((v.u >> 16) & 1u)) >> 16;
}
static __device__ __forceinline__ unsigned int packbf(float lo, float hi) {
  return f2bf(lo) | (f2bf(hi) << 16);
}

// ---- prep: fused column norms + bf16 operand layouts (identical to r8) ----
// grid 512 = which(2) x b(4) x ktile(64), 256 threads
__global__ __launch_bounds__(256) void prep_kernel(const float* __restrict__ bg,
                                                   const float* __restrict__ fg) {
  __shared__ float lds[64 * 65];   // [k][c], stride 65 (2-way banks everywhere)
  const int bid = blockIdx.x;
  const int kt = bid & 63, b = (bid >> 6) & 3, which = bid >> 8;
  const float* src = (which ? fg : bg) + (size_t)b * CC * HWN + kt * 64;
  const int tid = threadIdx.x;

  // stage tile transposed: thread loads [c][k-range] float4, writes lds[k][c]
  {
    int c = tid >> 2, k0 = (tid & 3) * 16;
#pragma unroll
    for (int j4 = 0; j4 < 4; ++j4) {
      float4 v = *(const float4*)(src + (size_t)c * HWN + k0 + 4 * j4);
      lds[(k0 + 4 * j4 + 0) * 65 + c] = v.x;
      lds[(k0 + 4 * j4 + 1) * 65 + c] = v.y;
      lds[(k0 + 4 * j4 + 2) * 65 + c] = v.z;
      lds[(k0 + 4 * j4 + 3) * 65 + c] = v.w;
    }
  }
  __syncthreads();

  const int k = tid >> 2, u = tid & 3;
  // column norm: 4 threads per k, each sums 16 c, combine via shfl
  float ss = 0.f;
#pragma unroll
  for (int j = 0; j < 16; ++j) {
    float v = lds[k * 65 + u * 16 + j];
    ss = fmaf(v, v, ss);
  }
  ss += __shfl_xor(ss, 1, 64);
  ss += __shfl_xor(ss, 2, 64);
  const float s = 1.0f / fmaxf(sqrtf(ss), 1e-12f);

  // write scaled transposed [b][k][c] bf16
  {
    unsigned int* gT32 = (unsigned int*)(which ? &g_fgT[0][0][0] : &g_bgT[0][0][0]);
    size_t R = (size_t)b * HWN + kt * 64 + k;
    unsigned int w8[8];
#pragma unroll
    for (int i = 0; i < 8; ++i) {
      int c2 = u * 16 + 2 * i;
      w8[i] = packbf(lds[k * 65 + c2] * s, lds[k * 65 + c2 + 1] * s);
    }
    *(uint4*)&gT32[R * 32 + u * 8]     = make_uint4(w8[0], w8[1], w8[2], w8[3]);
    *(uint4*)&gT32[R * 32 + u * 8 + 4] = make_uint4(w8[4], w8[5], w8[6], w8[7]);
  }

  // bg blocks also write raw cast, chunk-major: [b][kc][c][32]
  if (which == 0) {
    unsigned int* gN32 = (unsigned int*)&g_bgN[0][0][0][0];
    int cN = tid >> 2, vN = tid & 3;   // vN covers k = vN*16 .. +15 of this 64-k tile
    unsigned int n8[8];
#pragma unroll
    for (int i = 0; i < 8; ++i) {
      int kk = vN * 16 + 2 * i;
      n8[i] = packbf(lds[kk * 65 + cN], lds[(kk + 1) * 65 + cN]);
    }
    int kc = kt * 2 + (vN >> 1);           // global chunk index within batch
    size_t RN = (((size_t)b * NKC + kc) * CC + cN) * (KT / 2) + (vN & 1) * 8;
    *(uint4*)&gN32[RN]     = make_uint4(n8[0], n8[1], n8[2], n8[3]);
    *(uint4*)&gN32[RN + 4] = make_uint4(n8[4], n8[5], n8[6], n8[7]);
  }
}

// ---- flash attention: ALL-REGISTER main loop (zero LDS ops in the K-loop) ----
// r8 post-mortem: 70% stall at 2 waves/SIMD with traffic BELOW the L2 wall ->
// the in-loop LDS dependent chains (ds_read->QK lgkm wait; P write->wait->read
// roundtrip) are the残 floor. This round deletes them:
//  - QK A-frag (bgT[k][c], row=lane&15) loaded straight to regs (4x16B/chunk,
//    full 128B line use: 4 quads x 16B cover each row-half, both halves/iter).
//  - PV via v_mfma_f32_16x16x16_bf16 (K=16): its B-frag layout (col=q=lane&15,
//    rows k=quad*4+e) EXACTLY matches QK's C-layout (col=q=m16, k=quad*4+r), so
//    the softmax's packed bf16 pairs ARE the PV B-operand. No P buffer at all.
//  - PV A-frag: bf16x4 (c=16ct+m16, k=16i+quad*4) from chunk-major g_bgN, 8x8B.
// One counted vmcnt(12)/iter; no barriers, no ds ops. LDS only for the merge.
// LDS: [0,69632)  mO [8ks][64c][34] f32 (epilogue only)
//      [69632,71680) mL [8ks][64q] f32
#define ML_OFF 69632
#define SMEM_BYTES 71680
__global__ __launch_bounds__(512, 2) void attn_kernel(const float* __restrict__ fg,
                                                      const float* __restrict__ mask,
                                                      float* __restrict__ out) {
  __shared__ __align__(16) char smem[SMEM_BYTES];
  // bijective XCD swizzle (256 % 8 == 0): 2 XCDs per batch -> 2MB working set/L2
  const int wg = blockIdx.x;
  const int wgp = (wg & 7) * 32 + (wg >> 3);
  const int b = wgp >> 6;
  const int q0 = (wgp & 63) * QB;
  const int tid = threadIdx.x;
  const int lane = tid & 63;
  const int ks = tid >> 6;    // 0..7, private K-split (512 k each)
  const int m16 = lane & 15;
  const int quad = lane >> 4;

  // fg B-fragments (64 q), loaded once from global (L2)
  bf16x8 Bf[4][2];
#pragma unroll
  for (int qf = 0; qf < 4; ++qf)
#pragma unroll
    for (int h = 0; h < 2; ++h)
      Bf[qf][h] = *(const bf16x8*)&g_fgT[b][q0 + qf * 16 + m16][h * 32 + quad * 8];

  const unsigned short* const baseT = &g_bgT[b][ks * 512][0];      // row stride 64
  const unsigned short* const baseN = &g_bgN[b][ks * 16][0][0];    // 4KB blocks

  float* mL = (float*)(smem + ML_OFF);

  float l_run[4] = {0.f, 0.f, 0.f, 0.f};   // per-lane partial sums per q-frag
  f32x4 O[4][4];                            // [c-tile][q-frag]
#pragma unroll
  for (int t = 0; t < 4; ++t)
#pragma unroll
    for (int qf = 0; qf < 4; ++qf) O[t][qf] = (f32x4){0.f, 0.f, 0.f, 0.f};

  // register loads for one chunk: QK A-frags (2 k-rows x 2 c-halves) + PV A-frags
  auto loadT = [&](bf16x8 (&T)[2][2], int ch) {
#pragma unroll
    for (int i = 0; i < 2; ++i)
#pragma unroll
      for (int h = 0; h < 2; ++h)
        T[i][h] = *(const bf16x8*)(baseT + (size_t)(ch * 32 + i * 16 + m16) * CC +
                                   h * 32 + quad * 8);
  };
  auto loadA = [&](bf16x4 (&A)[4][2], int ch) {
#pragma unroll
    for (int ct = 0; ct < 4; ++ct)
#pragma unroll
      for (int i = 0; i < 2; ++i)
        A[ct][i] = *(const bf16x4*)(baseN + (size_t)ch * (CC * KT) +
                                    (ct * 16 + m16) * KT + i * 16 + quad * 4);
  };

  bf16x8 Ta[2][2], Tb[2][2];
  bf16x4 Aa[4][2], Ab[4][2];

  // one pipeline step: compute chunk `it` from regs T/A, prefetch it+1 into Tn/An
  auto iter = [&](int it, bf16x8 (&T)[2][2], bf16x4 (&A)[4][2],
                  bf16x8 (&Tn)[2][2], bf16x4 (&An)[4][2]) {
    if (it + 1 < NITER) {
      loadT(Tn, it + 1);     // 4 x 16B
      loadA(An, it + 1);     // 8 x 8B
      // oldest-12 wait: chunk-it's 12 loads complete; 12 newer stay in flight
      asm volatile("s_waitcnt vmcnt(12)" ::: "memory");
    } else {
      asm volatile("s_waitcnt vmcnt(0)" ::: "memory");
    }

    // QK: S[32k][64q] = (bg*sb)^T · (fg*sf)   (all-register, K=32 MFMA)
    f32x4 S[4][2];
    __builtin_amdgcn_s_setprio(1);
#pragma unroll
    for (int i = 0; i < 2; ++i)
#pragma unroll
      for (int qf = 0; qf < 4; ++qf) {
        f32x4 acc = {0.f, 0.f, 0.f, 0.f};
        acc = __builtin_amdgcn_mfma_f32_16x16x32_bf16(T[i][0], Bf[qf][0], acc, 0, 0, 0);
        acc = __builtin_amdgcn_mfma_f32_16x16x32_bf16(T[i][1], Bf[qf][1], acc, 0, 0, 0);
        S[qf][i] = acc;
      }
    __builtin_amdgcn_s_setprio(0);

    // fixed-max softmax: cosines, |s| <= 1 -> p = exp(s-1); pack pairs to bf16.
    // Packed regs ARE the PV B-fragments (K=16 layout match), no LDS roundtrip.
    bf16x4 Pp[4][2];
#pragma unroll
    for (int qf = 0; qf < 4; ++qf)
#pragma unroll
      for (int i = 0; i < 2; ++i) {
        float pe[4];
#pragma unroll
        for (int r = 0; r < 4; ++r) {
          pe[r] = __expf(S[qf][i][r] - 1.0f);
          l_run[qf] += pe[r];
        }
        union { float f; unsigned int u; } x0, x1, x2, x3;
        x0.f = pe[0]; x1.f = pe[1]; x2.f = pe[2]; x3.f = pe[3];
        union { unsigned int u[2]; bf16x4 v; } pk;
        pk.u[0] = __builtin_amdgcn_perm(x1.u + 0x8000u, x0.u + 0x8000u, 0x07060302u);
        pk.u[1] = __builtin_amdgcn_perm(x3.u + 0x8000u, x2.u + 0x8000u, 0x07060302u);
        Pp[qf][i] = pk.v;
      }

    // PV: O[c][q] += bg[c][k] · P[k][q]  via 2x K=16 MFMA per (ct,qf), all-register
    __builtin_amdgcn_s_setprio(1);
#pragma unroll
    for (int ct = 0; ct < 4; ++ct)
#pragma unroll
      for (int qf = 0; qf < 4; ++qf) {
        O[ct][qf] = __builtin_amdgcn_mfma_f32_16x16x16bf16_1k(A[ct][0], Pp[qf][0],
                                                              O[ct][qf], 0, 0, 0);
        O[ct][qf] = __builtin_amdgcn_mfma_f32_16x16x16bf16_1k(A[ct][1], Pp[qf][1],
                                                              O[ct][qf], 0, 0, 0);
      }
    __builtin_amdgcn_s_setprio(0);
  };

  // prologue: chunk 0 in flight (12 loads)
  loadT(Ta, 0);
  loadA(Aa, 0);

  for (int it2 = 0; it2 < NITER; it2 += 2) {
    iter(it2,     Ta, Aa, Tb, Ab);
    iter(it2 + 1, Tb, Ab, Ta, Aa);
  }

  // ---- merge 8 K-splits + epilogue (two q-half passes; mO in LDS) ----
#pragma unroll
  for (int qf = 0; qf < 4; ++qf) {
    l_run[qf] += __shfl_xor(l_run[qf], 16, 64);
    l_run[qf] += __shfl_xor(l_run[qf], 32, 64);
  }
  if (quad == 0) {
#pragma unroll
    for (int qf = 0; qf < 4; ++qf) mL[ks * 64 + qf * 16 + m16] = l_run[qf];
  }
  float* mO = (float*)smem;   // [8 ks][64 c][34]
  const float* fgB = fg + (size_t)b * CC * HWN;
  const float* mk = mask + (size_t)b * HWN;
  float* outB = out + (size_t)b * CC * HWN;

#pragma unroll
  for (int half = 0; half < 2; ++half) {
    __syncthreads();   // pass 0: mL visible; pass 1: prior reads done before overwrite
#pragma unroll
    for (int qh = 0; qh < 2; ++qh) {
      int qf = half * 2 + qh;
#pragma unroll
      for (int t = 0; t < 4; ++t)
#pragma unroll
        for (int r = 0; r < 4; ++r)
          mO[(ks * 64 + 16 * t + quad * 4 + r) * 34 + qh * 16 + m16] = O[t][qf][r];
    }
    __syncthreads();
    {
      int q = tid & 31, cb = tid >> 5;   // cb 0..15
      int qglob = q0 + half * 32 + q;
      float L = 0.f;
#pragma unroll
      for (int s = 0; s < 8; ++s) L += mL[s * 64 + half * 32 + q];
      float invL = 1.0f / L;
      float mv = mk[qglob];
#pragma unroll
      for (int e = 0; e < 4; ++e) {
        int c = cb * 4 + e;
        float acc = 0.f;
#pragma unroll
        for (int s = 0; s < 8; ++s) acc += mO[(s * 64 + c) * 34 + q];
        float att = acc * invL;
        float fgv = fgB[(size_t)c * HWN + qglob];
        outB[(size_t)c * HWN + qglob] = fgv + mv * (att - fgv);
      }
    }
  }
}

extern "C" void kernel_launch(void* const* d_in, const int* in_sizes, int n_in,
                              void* d_out, int out_size, void* d_ws, size_t ws_size,
                              hipStream_t stream) {
  const float* background = (const float*)d_in[0];
  const float* foreground = (const float*)d_in[1];
  const float* mask       = (const float*)d_in[2];
  float* out = (float*)d_out;
  prep_kernel<<<512, 256, 0, stream>>>(background, foreground);
  attn_kernel<<<dim3(HWN / QB * 4), 512, 0, stream>>>(foreground, mask, out);
}